// Round 18
// baseline (152.640 us; speedup 1.0000x reference)
//
#include <hip/hip_runtime.h>

namespace {
constexpr int BF = 4;        // frames
constexpr int NA = 4000;     // atoms per frame
constexpr int NPAD = 4096;   // padded K
constexpr int N8 = 512;      // NPAD/8 k-groups
constexpr int AD = 29;       // kx: 0..28
constexpr int CD = 57;       // ky/kz: -28..28
constexpr int NCH = 16;      // K-chunks (256 atoms each)
constexpr int KTC = 8;       // 32-atom k-tiles per chunk
constexpr float TWOPI_F = 6.28318530717958647692f;
constexpr float FPI = 39.47841760435743f;        // (2*pi)^2
constexpr float KSQMAX = 9.869604401089358f;     // (2*pi/2)^2
constexpr float SELF_C = 0.06349363593424097f;   // 1/(sigma*(2*pi)^1.5)
constexpr size_t YSTR = (size_t)N8 * 64 * 8;     // per-frame table elems = 262144
}

typedef short bfrag __attribute__((ext_vector_type(8)));
typedef float f32x4 __attribute__((ext_vector_type(4)));
typedef unsigned short u16x8 __attribute__((ext_vector_type(8)));
typedef _Float16 h2 __attribute__((ext_vector_type(2)));
typedef _Float16 h8 __attribute__((ext_vector_type(8)));

__device__ __forceinline__ unsigned short f2bf(float x) {  // RNE f32->bf16
  unsigned u = __float_as_uint(x);
  u += 0x7fffu + ((u >> 16) & 1u);
  return (unsigned short)(u >> 16);
}
__device__ __forceinline__ float2 cmul(float2 a, float2 b) {
  return make_float2(a.x * b.x - a.y * b.y, a.x * b.y + a.y * b.x);
}
__device__ __forceinline__ float2 cpow_m(float c, float s, int m) {
  float2 r = make_float2(1.f, 0.f);
  float2 x = make_float2(c, s);
  if (m & 1) r = x;
#pragma unroll
  for (int b = 1; b < 5; ++b) {
    x = cmul(x, x);
    const float2 t = cmul(r, x);
    if (m & (1 << b)) r = t;
  }
  return r;
}
__device__ __forceinline__ int swz(int byte) {   // R6-validated LDS swizzle
  return byte ^ (((byte >> 10) & 3) << 4);
}
__device__ __forceinline__ unsigned pk_h2(float a, float b) {
  union { h2 v; unsigned u; } p;
  p.v[0] = (_Float16)a; p.v[1] = (_Float16)b;
  return p.u;
}

// ---------------------------------------------------------------------------
// Fused prep (R8, unchanged). blockIdx.x < 128: Y(packed bf16)/Z tables.
// blockIdx.x >= 128: T table, bf16-packed u32 [f][a][n].
// ---------------------------------------------------------------------------
__global__ __launch_bounds__(256)
void ew_prep(const float* __restrict__ pos, const float* __restrict__ q,
             const float* __restrict__ cm,
             unsigned* __restrict__ Yp,
             unsigned short* __restrict__ Zpr, unsigned short* __restrict__ Zpi,
             unsigned* __restrict__ Tu)
{
  const int f = blockIdx.y;
  if (blockIdx.x < 128) {
    const int n8 = blockIdx.x * 4 + (threadIdx.x >> 6);   // 0..511
    const int col = threadIdx.x & 63;
    const int e = col - 28;
    const int m = (e < 0) ? -e : e;
    const bool valid = col < CD;
    const float by = cm[f * 9 + 4], bz = cm[f * 9 + 8];

    unsigned yp[8];
    float zr[8], zi[8];
#pragma unroll
    for (int i = 0; i < 8; ++i) {
      const int n = n8 * 8 + i;
      const bool ok = n < NA;
      const int gn = f * NA + n;
      const float y = ok ? pos[gn * 3 + 1] : 0.f;
      const float z = ok ? pos[gn * 3 + 2] : 0.f;
      {
        float rev = y / by; rev -= floorf(rev);
        float s, c; __sincosf(TWOPI_F * rev, &s, &c);
        float2 r = cpow_m(c, s, m);
        if (e < 0) r.y = -r.y;
        const float yr = valid ? r.x : 0.f;
        const float yi = valid ? r.y : 0.f;
        yp[i] = ((unsigned)f2bf(yi) << 16) | (unsigned)f2bf(yr);
      }
      {
        float rev = z / bz; rev -= floorf(rev);
        float s, c; __sincosf(TWOPI_F * rev, &s, &c);
        float2 r = cpow_m(c, s, m);
        if (e < 0) r.y = -r.y;
        zr[i] = valid ? r.x : 0.f;
        zi[i] = valid ? r.y : 0.f;
      }
    }
    const size_t base = (size_t)f * YSTR + (size_t)n8 * 512 + (size_t)col * 8;
    *(uint4*)(Yp + base)     = make_uint4(yp[0], yp[1], yp[2], yp[3]);
    *(uint4*)(Yp + base + 4) = make_uint4(yp[4], yp[5], yp[6], yp[7]);
    u16x8 zpr, zpi;
#pragma unroll
    for (int i = 0; i < 8; ++i) { zpr[i] = f2bf(zr[i]); zpi[i] = f2bf(zi[i]); }
    *(u16x8*)(Zpr + base) = zpr;
    *(u16x8*)(Zpi + base) = zpi;
  } else {
    const int n = (blockIdx.x - 128) * 256 + threadIdx.x;   // 0..4095
    const float bx = cm[f * 9 + 0];
    const bool ok = n < NA;
    const int gn = f * NA + n;
    const float x = ok ? pos[gn * 3 + 0] : 0.f;
    const float qq = ok ? q[gn] : 0.f;
    float rev = x / bx; rev -= floorf(rev);
    float s, c; __sincosf(TWOPI_F * rev, &s, &c);
    const float2 p = make_float2(c, s);
    float2 cur = make_float2(qq, 0.f);
    unsigned* tp = Tu + (size_t)f * AD * NPAD + n;
#pragma unroll 1
    for (int a = 0; a < AD; ++a) {
      tp[(size_t)a * NPAD] = ((unsigned)f2bf(cur.y) << 16) | (unsigned)f2bf(cur.x);
      cur = cmul(cur, p);
    }
  }
}

// ---------------------------------------------------------------------------
// MFMA S-accumulation — R17 body, UN-PAIRED: one a per block.
// Grid 1856 = 4f x 16ch x 29a -> 7.25 blocks/CU (~29 waves/CU resident).
// f-per-XCD-pair bijective decode; 16 KB LDS Z dbuf; 16B uint4 Sp stores.
// ---------------------------------------------------------------------------
__global__ __launch_bounds__(256, 6)
void ew_smfma(const unsigned* __restrict__ Yp,
              const unsigned short* __restrict__ Zpr,
              const unsigned short* __restrict__ Zpi,
              const unsigned* __restrict__ Tu, uint4* __restrict__ Sp4)
{
  const int bid = blockIdx.x;
  const int xcd = bid & 7;
  const int f = xcd >> 1;                 // 2 XCDs per frame
  const int half = xcd & 1;
  const int j = bid >> 3;                 // 0..231
  const int unit = half * 232 + j;        // 0..463
  const int ch = unit / 29;               // 0..15
  const int a = unit % 29;                // 0..28
  const int tid = threadIdx.x;
  const int w = tid >> 6, lane = tid & 63;
  const int g = lane >> 4, r16 = lane & 15;
  const int b0 = 16 * w;

  __shared__ unsigned short zbuf[2][2][2048];   // 16 KB

  f32x4 Sr[4], Si[4];
#pragma unroll
  for (int ct = 0; ct < 4; ++ct) {
    Sr[ct] = (f32x4){0.f, 0.f, 0.f, 0.f};
    Si[ct] = (f32x4){0.f, 0.f, 0.f, 0.f};
  }

  const unsigned* ybase = Yp + (size_t)f * YSTR + (size_t)(b0 + r16) * 8
                        + (size_t)g * 512 + (size_t)ch * KTC * 2048;
  const size_t zgbase = (size_t)f * YSTR + (size_t)ch * KTC * 2048 + (size_t)tid * 8;
  const unsigned* tp0 = Tu + ((size_t)f * AD + a) * NPAD + (size_t)ch * 256 + g * 8;

  char* const zb = (char*)&zbuf[0][0][0];
  const int wr_off = swz(tid * 16);
  const int rd_base = g * 1024 + r16 * 16;

  // prologue: stage kt 0
  u16x8 zr_st = *(const u16x8*)(Zpr + zgbase);
  u16x8 zi_st = *(const u16x8*)(Zpi + zgbase);
  *(u16x8*)(zb + wr_off) = zr_st;
  *(u16x8*)(zb + 4096 + wr_off) = zi_st;
  __syncthreads();

  for (int kt = 0; kt < KTC; ++kt) {
    const int knx = (kt + 1 < KTC) ? kt + 1 : kt;
    zr_st = *(const u16x8*)(Zpr + zgbase + (size_t)knx * 2048);
    zi_st = *(const u16x8*)(Zpi + zgbase + (size_t)knx * 2048);

    const uint4 yc0 = *(const uint4*)(ybase + (size_t)kt * 2048);
    const uint4 yc1 = *(const uint4*)(ybase + (size_t)kt * 2048 + 4);
    const uint4 ta0 = *(const uint4*)(tp0 + (size_t)kt * 32);
    const uint4 ta1 = *(const uint4*)(tp0 + (size_t)kt * 32 + 4);

    float yr[8], yi[8];
    {
      const unsigned yu[8] = {yc0.x, yc0.y, yc0.z, yc0.w,
                              yc1.x, yc1.y, yc1.z, yc1.w};
#pragma unroll
      for (int i = 0; i < 8; ++i) {
        yr[i] = __uint_as_float(yu[i] << 16);
        yi[i] = __uint_as_float(yu[i] & 0xffff0000u);
      }
    }
    char* const cb = zb + ((kt & 1) ? 8192 : 0);
    const bfrag Z0r = *(const bfrag*)(cb + swz(rd_base));
    const bfrag Z1r = *(const bfrag*)(cb + swz(rd_base + 256));
    const bfrag Z2r = *(const bfrag*)(cb + swz(rd_base + 512));
    const bfrag Z3r = *(const bfrag*)(cb + swz(rd_base + 768));
    const bfrag Z0i = *(const bfrag*)(cb + 4096 + swz(rd_base));
    const bfrag Z1i = *(const bfrag*)(cb + 4096 + swz(rd_base + 256));
    const bfrag Z2i = *(const bfrag*)(cb + 4096 + swz(rd_base + 512));
    const bfrag Z3i = *(const bfrag*)(cb + 4096 + swz(rd_base + 768));

    {
      const unsigned tu[8] = {ta0.x, ta0.y, ta0.z, ta0.w, ta1.x, ta1.y, ta1.z, ta1.w};
      float ur[8], ui[8];
#pragma unroll
      for (int i = 0; i < 8; ++i) {
        const float tr = __uint_as_float(tu[i] << 16);
        const float ti = __uint_as_float(tu[i] & 0xffff0000u);
        ur[i] = fmaf(tr, yr[i], -(ti * yi[i]));
        ui[i] = fmaf(tr, yi[i], ti * yr[i]);
      }
      union { unsigned u[4]; bfrag v; } UR, UI, UN;
#pragma unroll
      for (int k = 0; k < 4; ++k) {
        asm("v_cvt_pk_bf16_f32 %0, %1, %2" : "=v"(UR.u[k]) : "v"(ur[2*k]), "v"(ur[2*k+1]));
        asm("v_cvt_pk_bf16_f32 %0, %1, %2" : "=v"(UI.u[k]) : "v"(ui[2*k]), "v"(ui[2*k+1]));
      }
#pragma unroll
      for (int k = 0; k < 4; ++k) UN.u[k] = UI.u[k] ^ 0x80008000u;
      Sr[0] = __builtin_amdgcn_mfma_f32_16x16x32_bf16(UR.v, Z0r, Sr[0], 0, 0, 0);
      Sr[0] = __builtin_amdgcn_mfma_f32_16x16x32_bf16(UN.v, Z0i, Sr[0], 0, 0, 0);
      Si[0] = __builtin_amdgcn_mfma_f32_16x16x32_bf16(UR.v, Z0i, Si[0], 0, 0, 0);
      Si[0] = __builtin_amdgcn_mfma_f32_16x16x32_bf16(UI.v, Z0r, Si[0], 0, 0, 0);
      Sr[1] = __builtin_amdgcn_mfma_f32_16x16x32_bf16(UR.v, Z1r, Sr[1], 0, 0, 0);
      Sr[1] = __builtin_amdgcn_mfma_f32_16x16x32_bf16(UN.v, Z1i, Sr[1], 0, 0, 0);
      Si[1] = __builtin_amdgcn_mfma_f32_16x16x32_bf16(UR.v, Z1i, Si[1], 0, 0, 0);
      Si[1] = __builtin_amdgcn_mfma_f32_16x16x32_bf16(UI.v, Z1r, Si[1], 0, 0, 0);
      Sr[2] = __builtin_amdgcn_mfma_f32_16x16x32_bf16(UR.v, Z2r, Sr[2], 0, 0, 0);
      Sr[2] = __builtin_amdgcn_mfma_f32_16x16x32_bf16(UN.v, Z2i, Sr[2], 0, 0, 0);
      Si[2] = __builtin_amdgcn_mfma_f32_16x16x32_bf16(UR.v, Z2i, Si[2], 0, 0, 0);
      Si[2] = __builtin_amdgcn_mfma_f32_16x16x32_bf16(UI.v, Z2r, Si[2], 0, 0, 0);
      Sr[3] = __builtin_amdgcn_mfma_f32_16x16x32_bf16(UR.v, Z3r, Sr[3], 0, 0, 0);
      Sr[3] = __builtin_amdgcn_mfma_f32_16x16x32_bf16(UN.v, Z3i, Sr[3], 0, 0, 0);
      Si[3] = __builtin_amdgcn_mfma_f32_16x16x32_bf16(UR.v, Z3i, Si[3], 0, 0, 0);
      Si[3] = __builtin_amdgcn_mfma_f32_16x16x32_bf16(UI.v, Z3r, Si[3], 0, 0, 0);
    }
    char* const nb = zb + ((kt & 1) ? 0 : 8192);
    *(u16x8*)(nb + wr_off) = zr_st;
    *(u16x8*)(nb + 4096 + wr_off) = zi_st;
    __syncthreads();
  }

  // ---- 16B/lane Sp stores: e = ct*1024 + tid*4 + rg; uint4 idx = e/4 ----
  const size_t soq = ((((size_t)ch * BF + f) * AD + a) * 4096) >> 2;
#pragma unroll
  for (int ct = 0; ct < 4; ++ct) {
    Sp4[soq + ct * 256 + tid] =
        make_uint4(pk_h2(Sr[ct][0], Si[ct][0]), pk_h2(Sr[ct][1], Si[ct][1]),
                   pk_h2(Sr[ct][2], Si[ct][2]), pk_h2(Sr[ct][3], Si[ct][3]));
  }
}

// ---------------------------------------------------------------------------
// Reduce — R17 byte-identical (vectorized h8 loads, e=ct*1024+tid2*4+rg decode).
// ---------------------------------------------------------------------------
__global__ __launch_bounds__(256)
void ew_reduce(const h2* __restrict__ SpH, const float* __restrict__ cm,
               const float* __restrict__ q, float* __restrict__ out)
{
  const int a = blockIdx.y, f = blockIdx.z;
  const int t = blockIdx.x * 256 + threadIdx.x;   // 0..1023
  const int cell0 = t * 4;
  const int ct = t >> 8;
  const int tid2 = t & 255;
  const int w2 = tid2 >> 6, lane2 = tid2 & 63;
  const int c = ct * 16 + (lane2 & 15);
  const int bbase = w2 * 16 + (lane2 >> 4) * 4;   // + rg
  float Sr[4] = {0.f, 0.f, 0.f, 0.f}, Si[4] = {0.f, 0.f, 0.f, 0.f};
  const size_t base = ((size_t)f * AD + a) * 4096 + cell0;
  constexpr size_t CHSTR = (size_t)BF * AD * 4096;
#pragma unroll
  for (int ch = 0; ch < NCH; ++ch) {
    const h8 v = *(const h8*)(SpH + (size_t)ch * CHSTR + base);
#pragma unroll
    for (int k = 0; k < 4; ++k) {
      Sr[k] += (float)v[2 * k];
      Si[k] += (float)v[2 * k + 1];
    }
  }
  const float bx = cm[f * 9 + 0], by = cm[f * 9 + 4], bz = cm[f * 9 + 8];
  const float invV = 1.f / (bx * by * bz);
  const float fac = (a > 0) ? 2.f : 1.f;
  const float aterm = (float)(a * a) / (bx * bx);
  const int cv = c - 28;
  const float cterm = (float)(cv * cv) / (bz * bz);
  float val = 0.f;
#pragma unroll
  for (int k = 0; k < 4; ++k) {
    const int bv = bbase + k - 28;
    const float ksq = FPI * (aterm + (float)(bv * bv) / (by * by) + cterm);
    if (ksq > 0.f && ksq <= KSQMAX) {
      const float wgt = __expf(-0.5f * ksq) / ksq * fac * invV;
      val = fmaf(wgt, Sr[k] * Sr[k] + Si[k] * Si[k], val);
    }
  }
  for (int off = 32; off > 0; off >>= 1) val += __shfl_down(val, off);
  __shared__ float wsum[4];
  const int w = threadIdx.x >> 6;
  if ((threadIdx.x & 63) == 0) wsum[w] = val;
  __syncthreads();
  if (threadIdx.x == 0)
    atomicAdd(&out[f], wsum[0] + wsum[1] + wsum[2] + wsum[3]);

  if (a == 0 && blockIdx.x == 0) {   // fold in self-energy
    __syncthreads();
    float s = 0.f;
    for (int i = threadIdx.x; i < NA; i += 256) {
      const float qq = q[f * NA + i];
      s += qq * qq;
    }
    for (int off = 32; off > 0; off >>= 1) s += __shfl_down(s, off);
    if ((threadIdx.x & 63) == 0) wsum[w] = s;
    __syncthreads();
    if (threadIdx.x == 0)
      atomicAdd(&out[f], -(wsum[0] + wsum[1] + wsum[2] + wsum[3]) * SELF_C);
  }
}

extern "C" void kernel_launch(void* const* d_in, const int* in_sizes, int n_in,
                              void* d_out, int out_size, void* d_ws, size_t ws_size,
                              hipStream_t stream) {
  const float* pos = (const float*)d_in[0];   // (B*N, 3)
  const float* q   = (const float*)d_in[1];   // (B*N, 1)
  const float* cm  = (const float*)d_in[2];   // (B, 3, 3)
  float* out = (float*)d_out;                 // (B,)

  char* ws = (char*)d_ws;
  const size_t MB = 1024 * 1024;
  unsigned* Yp = (unsigned*)(ws);                         // 4 MB
  unsigned short* Zpr = (unsigned short*)(ws + 4 * MB);   // 2 MB
  unsigned short* Zpi = (unsigned short*)(ws + 6 * MB);   // 2 MB
  unsigned* Tu = (unsigned*)(ws + 8 * MB);                // 1.9 MB
  h2* SpH = (h2*)(ws + 10 * MB);                          // 30.4 MB
  uint4* Sp4 = (uint4*)SpH;

  hipMemsetAsync(d_out, 0, out_size * sizeof(float), stream);
  ew_prep<<<dim3(144, BF), 256, 0, stream>>>(pos, q, cm, Yp, Zpr, Zpi, Tu);
  ew_smfma<<<dim3(1856), 256, 0, stream>>>(Yp, Zpr, Zpi, Tu, Sp4);
  ew_reduce<<<dim3(4, AD, BF), 256, 0, stream>>>(SpH, cm, q, out);
}

// Round 20
// 69.206 us; speedup vs baseline: 2.2056x; 2.2056x over previous
//
#include <hip/hip_runtime.h>

namespace {
constexpr int BF = 4;        // frames
constexpr int NA = 4000;     // atoms per frame
constexpr int NPAD = 4096;   // padded K
constexpr int N8 = 512;      // NPAD/8 k-groups
constexpr int AD = 29;       // kx: 0..28
constexpr int CD = 57;       // ky/kz: -28..28
constexpr int NCH = 16;      // K-chunks (256 atoms each)
constexpr int KTC = 8;       // 32-atom k-tiles per chunk
constexpr float TWOPI_F = 6.28318530717958647692f;
constexpr float FPI = 39.47841760435743f;        // (2*pi)^2
constexpr float KSQMAX = 9.869604401089358f;     // (2*pi/2)^2
constexpr float SELF_C = 0.06349363593424097f;   // 1/(sigma*(2*pi)^1.5)
constexpr size_t YSTR = (size_t)N8 * 64 * 8;     // per-frame table elems = 262144
}

typedef short bfrag __attribute__((ext_vector_type(8)));
typedef float f32x4 __attribute__((ext_vector_type(4)));
typedef unsigned short u16x8 __attribute__((ext_vector_type(8)));
typedef unsigned u32x4 __attribute__((ext_vector_type(4)));
typedef _Float16 h2 __attribute__((ext_vector_type(2)));
typedef _Float16 h8 __attribute__((ext_vector_type(8)));

__device__ __forceinline__ unsigned short f2bf(float x) {  // RNE f32->bf16
  unsigned u = __float_as_uint(x);
  u += 0x7fffu + ((u >> 16) & 1u);
  return (unsigned short)(u >> 16);
}
__device__ __forceinline__ float2 cmul(float2 a, float2 b) {
  return make_float2(a.x * b.x - a.y * b.y, a.x * b.y + a.y * b.x);
}
__device__ __forceinline__ float2 cpow_m(float c, float s, int m) {
  float2 r = make_float2(1.f, 0.f);
  float2 x = make_float2(c, s);
  if (m & 1) r = x;
#pragma unroll
  for (int b = 1; b < 5; ++b) {
    x = cmul(x, x);
    const float2 t = cmul(r, x);
    if (m & (1 << b)) r = t;
  }
  return r;
}
__device__ __forceinline__ int swz(int byte) {   // R6-validated LDS swizzle
  return byte ^ (((byte >> 10) & 3) << 4);
}
__device__ __forceinline__ unsigned pk_h2(float a, float b) {
  union { h2 v; unsigned u; } p;
  p.v[0] = (_Float16)a; p.v[1] = (_Float16)b;
  return p.u;
}

// ---------------------------------------------------------------------------
// Fused prep (R8 bodies) + out zeroing (replaces the memset dispatch;
// R12-proven mechanism). blockIdx.x < 128: Y/Z tables. >= 128: T table.
// ---------------------------------------------------------------------------
__global__ __launch_bounds__(256)
void ew_prep(const float* __restrict__ pos, const float* __restrict__ q,
             const float* __restrict__ cm,
             unsigned* __restrict__ Yp,
             unsigned short* __restrict__ Zpr, unsigned short* __restrict__ Zpi,
             unsigned* __restrict__ Tu, float* __restrict__ out)
{
  const int f = blockIdx.y;
  if (blockIdx.x == 0 && f == 0 && threadIdx.x < BF) out[threadIdx.x] = 0.f;
  if (blockIdx.x < 128) {
    const int n8 = blockIdx.x * 4 + (threadIdx.x >> 6);   // 0..511
    const int col = threadIdx.x & 63;
    const int e = col - 28;
    const int m = (e < 0) ? -e : e;
    const bool valid = col < CD;
    const float by = cm[f * 9 + 4], bz = cm[f * 9 + 8];

    unsigned yp[8];
    float zr[8], zi[8];
#pragma unroll
    for (int i = 0; i < 8; ++i) {
      const int n = n8 * 8 + i;
      const bool ok = n < NA;
      const int gn = f * NA + n;
      const float y = ok ? pos[gn * 3 + 1] : 0.f;
      const float z = ok ? pos[gn * 3 + 2] : 0.f;
      {
        float rev = y / by; rev -= floorf(rev);
        float s, c; __sincosf(TWOPI_F * rev, &s, &c);
        float2 r = cpow_m(c, s, m);
        if (e < 0) r.y = -r.y;
        const float yr = valid ? r.x : 0.f;
        const float yi = valid ? r.y : 0.f;
        yp[i] = ((unsigned)f2bf(yi) << 16) | (unsigned)f2bf(yr);
      }
      {
        float rev = z / bz; rev -= floorf(rev);
        float s, c; __sincosf(TWOPI_F * rev, &s, &c);
        float2 r = cpow_m(c, s, m);
        if (e < 0) r.y = -r.y;
        zr[i] = valid ? r.x : 0.f;
        zi[i] = valid ? r.y : 0.f;
      }
    }
    const size_t base = (size_t)f * YSTR + (size_t)n8 * 512 + (size_t)col * 8;
    *(uint4*)(Yp + base)     = make_uint4(yp[0], yp[1], yp[2], yp[3]);
    *(uint4*)(Yp + base + 4) = make_uint4(yp[4], yp[5], yp[6], yp[7]);
    u16x8 zpr, zpi;
#pragma unroll
    for (int i = 0; i < 8; ++i) { zpr[i] = f2bf(zr[i]); zpi[i] = f2bf(zi[i]); }
    *(u16x8*)(Zpr + base) = zpr;
    *(u16x8*)(Zpi + base) = zpi;
  } else {
    const int n = (blockIdx.x - 128) * 256 + threadIdx.x;   // 0..4095
    const float bx = cm[f * 9 + 0];
    const bool ok = n < NA;
    const int gn = f * NA + n;
    const float x = ok ? pos[gn * 3 + 0] : 0.f;
    const float qq = ok ? q[gn] : 0.f;
    float rev = x / bx; rev -= floorf(rev);
    float s, c; __sincosf(TWOPI_F * rev, &s, &c);
    const float2 p = make_float2(c, s);
    float2 cur = make_float2(qq, 0.f);
    unsigned* tp = Tu + (size_t)f * AD * NPAD + n;
#pragma unroll 1
    for (int a = 0; a < AD; ++a) {
      tp[(size_t)a * NPAD] = ((unsigned)f2bf(cur.y) << 16) | (unsigned)f2bf(cur.x);
      cur = cmul(cur, p);
    }
  }
}

// ---------------------------------------------------------------------------
// MFMA S-accumulation — R17 byte-identical EXCEPT nontemporal Sp stores
// (full-line 16B/lane via ext_vector u32x4 -> no L2 write-allocate).
// ---------------------------------------------------------------------------
__global__ __launch_bounds__(256, 4)
void ew_smfma(const unsigned* __restrict__ Yp,
              const unsigned short* __restrict__ Zpr,
              const unsigned short* __restrict__ Zpi,
              const unsigned* __restrict__ Tu, u32x4* __restrict__ Sp4)
{
  // f-per-XCD-pair bijective decode (960 blocks) — R13-validated
  const int bid = blockIdx.x;
  const int xcd = bid & 7;
  const int f = xcd >> 1;                 // 2 XCDs per frame
  const int half = xcd & 1;
  const int j = bid >> 3;                 // 0..119
  const int unit = half * 120 + j;        // 0..239
  const int ch = unit / 15;               // 0..15
  const int ag = unit % 15;               // 0..14
  const int a0 = 2 * ag, a1 = a0 + 1;
  const bool has1 = a1 < AD;
  const int tid = threadIdx.x;
  const int w = tid >> 6, lane = tid & 63;
  const int g = lane >> 4, r16 = lane & 15;
  const int b0 = 16 * w;

  __shared__ unsigned short zbuf[2][2][2048];   // 16 KB

  f32x4 S0r[4], S0i[4], S1r[4], S1i[4];
#pragma unroll
  for (int ct = 0; ct < 4; ++ct) {
    S0r[ct] = (f32x4){0.f, 0.f, 0.f, 0.f}; S0i[ct] = (f32x4){0.f, 0.f, 0.f, 0.f};
    S1r[ct] = (f32x4){0.f, 0.f, 0.f, 0.f}; S1i[ct] = (f32x4){0.f, 0.f, 0.f, 0.f};
  }

  const unsigned* ybase = Yp + (size_t)f * YSTR + (size_t)(b0 + r16) * 8
                        + (size_t)g * 512 + (size_t)ch * KTC * 2048;
  const size_t zgbase = (size_t)f * YSTR + (size_t)ch * KTC * 2048 + (size_t)tid * 8;
  const unsigned* tp0 = Tu + ((size_t)f * AD + a0) * NPAD + (size_t)ch * 256 + g * 8;
  const unsigned* tp1 = Tu + ((size_t)f * AD + (has1 ? a1 : a0)) * NPAD
                      + (size_t)ch * 256 + g * 8;

  char* const zb = (char*)&zbuf[0][0][0];
  const int wr_off = swz(tid * 16);
  const int rd_base = g * 1024 + r16 * 16;

  // prologue: stage kt 0
  u16x8 zr_st = *(const u16x8*)(Zpr + zgbase);
  u16x8 zi_st = *(const u16x8*)(Zpi + zgbase);
  *(u16x8*)(zb + wr_off) = zr_st;
  *(u16x8*)(zb + 4096 + wr_off) = zi_st;
  __syncthreads();

  for (int kt = 0; kt < KTC; ++kt) {
    const int knx = (kt + 1 < KTC) ? kt + 1 : kt;
    zr_st = *(const u16x8*)(Zpr + zgbase + (size_t)knx * 2048);
    zi_st = *(const u16x8*)(Zpi + zgbase + (size_t)knx * 2048);

    const uint4 yc0 = *(const uint4*)(ybase + (size_t)kt * 2048);
    const uint4 yc1 = *(const uint4*)(ybase + (size_t)kt * 2048 + 4);
    const uint4 ta0 = *(const uint4*)(tp0 + (size_t)kt * 32);
    const uint4 ta1 = *(const uint4*)(tp0 + (size_t)kt * 32 + 4);
    const uint4 tb0 = *(const uint4*)(tp1 + (size_t)kt * 32);
    const uint4 tb1 = *(const uint4*)(tp1 + (size_t)kt * 32 + 4);

    float yr[8], yi[8];
    {
      const unsigned yu[8] = {yc0.x, yc0.y, yc0.z, yc0.w,
                              yc1.x, yc1.y, yc1.z, yc1.w};
#pragma unroll
      for (int i = 0; i < 8; ++i) {
        yr[i] = __uint_as_float(yu[i] << 16);
        yi[i] = __uint_as_float(yu[i] & 0xffff0000u);
      }
    }
    char* const cb = zb + ((kt & 1) ? 8192 : 0);
    const bfrag Z0r = *(const bfrag*)(cb + swz(rd_base));
    const bfrag Z1r = *(const bfrag*)(cb + swz(rd_base + 256));
    const bfrag Z2r = *(const bfrag*)(cb + swz(rd_base + 512));
    const bfrag Z3r = *(const bfrag*)(cb + swz(rd_base + 768));
    const bfrag Z0i = *(const bfrag*)(cb + 4096 + swz(rd_base));
    const bfrag Z1i = *(const bfrag*)(cb + 4096 + swz(rd_base + 256));
    const bfrag Z2i = *(const bfrag*)(cb + 4096 + swz(rd_base + 512));
    const bfrag Z3i = *(const bfrag*)(cb + 4096 + swz(rd_base + 768));

    // ---- a0 ----
    {
      const unsigned tu[8] = {ta0.x, ta0.y, ta0.z, ta0.w, ta1.x, ta1.y, ta1.z, ta1.w};
      float ur[8], ui[8];
#pragma unroll
      for (int i = 0; i < 8; ++i) {
        const float tr = __uint_as_float(tu[i] << 16);
        const float ti = __uint_as_float(tu[i] & 0xffff0000u);
        ur[i] = fmaf(tr, yr[i], -(ti * yi[i]));
        ui[i] = fmaf(tr, yi[i], ti * yr[i]);
      }
      union { unsigned u[4]; bfrag v; } UR, UI, UN;
#pragma unroll
      for (int k = 0; k < 4; ++k) {
        asm("v_cvt_pk_bf16_f32 %0, %1, %2" : "=v"(UR.u[k]) : "v"(ur[2*k]), "v"(ur[2*k+1]));
        asm("v_cvt_pk_bf16_f32 %0, %1, %2" : "=v"(UI.u[k]) : "v"(ui[2*k]), "v"(ui[2*k+1]));
      }
#pragma unroll
      for (int k = 0; k < 4; ++k) UN.u[k] = UI.u[k] ^ 0x80008000u;
      S0r[0] = __builtin_amdgcn_mfma_f32_16x16x32_bf16(UR.v, Z0r, S0r[0], 0, 0, 0);
      S0r[0] = __builtin_amdgcn_mfma_f32_16x16x32_bf16(UN.v, Z0i, S0r[0], 0, 0, 0);
      S0i[0] = __builtin_amdgcn_mfma_f32_16x16x32_bf16(UR.v, Z0i, S0i[0], 0, 0, 0);
      S0i[0] = __builtin_amdgcn_mfma_f32_16x16x32_bf16(UI.v, Z0r, S0i[0], 0, 0, 0);
      S0r[1] = __builtin_amdgcn_mfma_f32_16x16x32_bf16(UR.v, Z1r, S0r[1], 0, 0, 0);
      S0r[1] = __builtin_amdgcn_mfma_f32_16x16x32_bf16(UN.v, Z1i, S0r[1], 0, 0, 0);
      S0i[1] = __builtin_amdgcn_mfma_f32_16x16x32_bf16(UR.v, Z1i, S0i[1], 0, 0, 0);
      S0i[1] = __builtin_amdgcn_mfma_f32_16x16x32_bf16(UI.v, Z1r, S0i[1], 0, 0, 0);
      S0r[2] = __builtin_amdgcn_mfma_f32_16x16x32_bf16(UR.v, Z2r, S0r[2], 0, 0, 0);
      S0r[2] = __builtin_amdgcn_mfma_f32_16x16x32_bf16(UN.v, Z2i, S0r[2], 0, 0, 0);
      S0i[2] = __builtin_amdgcn_mfma_f32_16x16x32_bf16(UR.v, Z2i, S0i[2], 0, 0, 0);
      S0i[2] = __builtin_amdgcn_mfma_f32_16x16x32_bf16(UI.v, Z2r, S0i[2], 0, 0, 0);
      S0r[3] = __builtin_amdgcn_mfma_f32_16x16x32_bf16(UR.v, Z3r, S0r[3], 0, 0, 0);
      S0r[3] = __builtin_amdgcn_mfma_f32_16x16x32_bf16(UN.v, Z3i, S0r[3], 0, 0, 0);
      S0i[3] = __builtin_amdgcn_mfma_f32_16x16x32_bf16(UR.v, Z3i, S0i[3], 0, 0, 0);
      S0i[3] = __builtin_amdgcn_mfma_f32_16x16x32_bf16(UI.v, Z3r, S0i[3], 0, 0, 0);
    }
    // ---- a1 ----
    if (has1) {
      const unsigned tu[8] = {tb0.x, tb0.y, tb0.z, tb0.w, tb1.x, tb1.y, tb1.z, tb1.w};
      float ur[8], ui[8];
#pragma unroll
      for (int i = 0; i < 8; ++i) {
        const float tr = __uint_as_float(tu[i] << 16);
        const float ti = __uint_as_float(tu[i] & 0xffff0000u);
        ur[i] = fmaf(tr, yr[i], -(ti * yi[i]));
        ui[i] = fmaf(tr, yi[i], ti * yr[i]);
      }
      union { unsigned u[4]; bfrag v; } UR, UI, UN;
#pragma unroll
      for (int k = 0; k < 4; ++k) {
        asm("v_cvt_pk_bf16_f32 %0, %1, %2" : "=v"(UR.u[k]) : "v"(ur[2*k]), "v"(ur[2*k+1]));
        asm("v_cvt_pk_bf16_f32 %0, %1, %2" : "=v"(UI.u[k]) : "v"(ui[2*k]), "v"(ui[2*k+1]));
      }
#pragma unroll
      for (int k = 0; k < 4; ++k) UN.u[k] = UI.u[k] ^ 0x80008000u;
      S1r[0] = __builtin_amdgcn_mfma_f32_16x16x32_bf16(UR.v, Z0r, S1r[0], 0, 0, 0);
      S1r[0] = __builtin_amdgcn_mfma_f32_16x16x32_bf16(UN.v, Z0i, S1r[0], 0, 0, 0);
      S1i[0] = __builtin_amdgcn_mfma_f32_16x16x32_bf16(UR.v, Z0i, S1i[0], 0, 0, 0);
      S1i[0] = __builtin_amdgcn_mfma_f32_16x16x32_bf16(UI.v, Z0r, S1i[0], 0, 0, 0);
      S1r[1] = __builtin_amdgcn_mfma_f32_16x16x32_bf16(UR.v, Z1r, S1r[1], 0, 0, 0);
      S1r[1] = __builtin_amdgcn_mfma_f32_16x16x32_bf16(UN.v, Z1i, S1r[1], 0, 0, 0);
      S1i[1] = __builtin_amdgcn_mfma_f32_16x16x32_bf16(UR.v, Z1i, S1i[1], 0, 0, 0);
      S1i[1] = __builtin_amdgcn_mfma_f32_16x16x32_bf16(UI.v, Z1r, S1i[1], 0, 0, 0);
      S1r[2] = __builtin_amdgcn_mfma_f32_16x16x32_bf16(UR.v, Z2r, S1r[2], 0, 0, 0);
      S1r[2] = __builtin_amdgcn_mfma_f32_16x16x32_bf16(UN.v, Z2i, S1r[2], 0, 0, 0);
      S1i[2] = __builtin_amdgcn_mfma_f32_16x16x32_bf16(UR.v, Z2i, S1i[2], 0, 0, 0);
      S1i[2] = __builtin_amdgcn_mfma_f32_16x16x32_bf16(UI.v, Z2r, S1i[2], 0, 0, 0);
      S1r[3] = __builtin_amdgcn_mfma_f32_16x16x32_bf16(UR.v, Z3r, S1r[3], 0, 0, 0);
      S1r[3] = __builtin_amdgcn_mfma_f32_16x16x32_bf16(UN.v, Z3i, S1r[3], 0, 0, 0);
      S1i[3] = __builtin_amdgcn_mfma_f32_16x16x32_bf16(UR.v, Z3i, S1i[3], 0, 0, 0);
      S1i[3] = __builtin_amdgcn_mfma_f32_16x16x32_bf16(UI.v, Z3r, S1i[3], 0, 0, 0);
    }
    char* const nb = zb + ((kt & 1) ? 0 : 8192);
    *(u16x8*)(nb + wr_off) = zr_st;
    *(u16x8*)(nb + 4096 + wr_off) = zi_st;
    __syncthreads();
  }

  // ---- nontemporal 16B/lane Sp stores: e = ct*1024 + tid*4 + rg ----
  const size_t so0q = ((((size_t)ch * BF + f) * AD + a0) * 4096) >> 2;
#pragma unroll
  for (int ct = 0; ct < 4; ++ct) {
    u32x4 v;
    v[0] = pk_h2(S0r[ct][0], S0i[ct][0]);
    v[1] = pk_h2(S0r[ct][1], S0i[ct][1]);
    v[2] = pk_h2(S0r[ct][2], S0i[ct][2]);
    v[3] = pk_h2(S0r[ct][3], S0i[ct][3]);
    __builtin_nontemporal_store(v, &Sp4[so0q + ct * 256 + tid]);
  }
  if (has1) {
    const size_t so1q = ((((size_t)ch * BF + f) * AD + a1) * 4096) >> 2;
#pragma unroll
    for (int ct = 0; ct < 4; ++ct) {
      u32x4 v;
      v[0] = pk_h2(S1r[ct][0], S1i[ct][0]);
      v[1] = pk_h2(S1r[ct][1], S1i[ct][1]);
      v[2] = pk_h2(S1r[ct][2], S1i[ct][2]);
      v[3] = pk_h2(S1r[ct][3], S1i[ct][3]);
      __builtin_nontemporal_store(v, &Sp4[so1q + ct * 256 + tid]);
    }
  }
}

// ---------------------------------------------------------------------------
// Reduce — R17 byte-identical (vectorized h8 loads, e=ct*1024+tid2*4+rg decode).
// ---------------------------------------------------------------------------
__global__ __launch_bounds__(256)
void ew_reduce(const h2* __restrict__ SpH, const float* __restrict__ cm,
               const float* __restrict__ q, float* __restrict__ out)
{
  const int a = blockIdx.y, f = blockIdx.z;
  const int t = blockIdx.x * 256 + threadIdx.x;   // 0..1023
  const int cell0 = t * 4;
  const int ct = t >> 8;
  const int tid2 = t & 255;
  const int w2 = tid2 >> 6, lane2 = tid2 & 63;
  const int c = ct * 16 + (lane2 & 15);
  const int bbase = w2 * 16 + (lane2 >> 4) * 4;   // + rg
  float Sr[4] = {0.f, 0.f, 0.f, 0.f}, Si[4] = {0.f, 0.f, 0.f, 0.f};
  const size_t base = ((size_t)f * AD + a) * 4096 + cell0;
  constexpr size_t CHSTR = (size_t)BF * AD * 4096;
#pragma unroll
  for (int ch = 0; ch < NCH; ++ch) {
    const h8 v = *(const h8*)(SpH + (size_t)ch * CHSTR + base);
#pragma unroll
    for (int k = 0; k < 4; ++k) {
      Sr[k] += (float)v[2 * k];
      Si[k] += (float)v[2 * k + 1];
    }
  }
  const float bx = cm[f * 9 + 0], by = cm[f * 9 + 4], bz = cm[f * 9 + 8];
  const float invV = 1.f / (bx * by * bz);
  const float fac = (a > 0) ? 2.f : 1.f;
  const float aterm = (float)(a * a) / (bx * bx);
  const int cv = c - 28;
  const float cterm = (float)(cv * cv) / (bz * bz);
  float val = 0.f;
#pragma unroll
  for (int k = 0; k < 4; ++k) {
    const int bv = bbase + k - 28;
    const float ksq = FPI * (aterm + (float)(bv * bv) / (by * by) + cterm);
    if (ksq > 0.f && ksq <= KSQMAX) {
      const float wgt = __expf(-0.5f * ksq) / ksq * fac * invV;
      val = fmaf(wgt, Sr[k] * Sr[k] + Si[k] * Si[k], val);
    }
  }
  for (int off = 32; off > 0; off >>= 1) val += __shfl_down(val, off);
  __shared__ float wsum[4];
  const int w = threadIdx.x >> 6;
  if ((threadIdx.x & 63) == 0) wsum[w] = val;
  __syncthreads();
  if (threadIdx.x == 0)
    atomicAdd(&out[f], wsum[0] + wsum[1] + wsum[2] + wsum[3]);

  if (a == 0 && blockIdx.x == 0) {   // fold in self-energy
    __syncthreads();
    float s = 0.f;
    for (int i = threadIdx.x; i < NA; i += 256) {
      const float qq = q[f * NA + i];
      s += qq * qq;
    }
    for (int off = 32; off > 0; off >>= 1) s += __shfl_down(s, off);
    if ((threadIdx.x & 63) == 0) wsum[w] = s;
    __syncthreads();
    if (threadIdx.x == 0)
      atomicAdd(&out[f], -(wsum[0] + wsum[1] + wsum[2] + wsum[3]) * SELF_C);
  }
}

extern "C" void kernel_launch(void* const* d_in, const int* in_sizes, int n_in,
                              void* d_out, int out_size, void* d_ws, size_t ws_size,
                              hipStream_t stream) {
  const float* pos = (const float*)d_in[0];   // (B*N, 3)
  const float* q   = (const float*)d_in[1];   // (B*N, 1)
  const float* cm  = (const float*)d_in[2];   // (B, 3, 3)
  float* out = (float*)d_out;                 // (B,)

  char* ws = (char*)d_ws;
  const size_t MB = 1024 * 1024;
  unsigned* Yp = (unsigned*)(ws);                         // 4 MB
  unsigned short* Zpr = (unsigned short*)(ws + 4 * MB);   // 2 MB
  unsigned short* Zpi = (unsigned short*)(ws + 6 * MB);   // 2 MB
  unsigned* Tu = (unsigned*)(ws + 8 * MB);                // 1.9 MB
  h2* SpH = (h2*)(ws + 10 * MB);                          // 30.4 MB
  u32x4* Sp4 = (u32x4*)SpH;

  ew_prep<<<dim3(144, BF), 256, 0, stream>>>(pos, q, cm, Yp, Zpr, Zpi, Tu, out);
  ew_smfma<<<dim3(960), 256, 0, stream>>>(Yp, Zpr, Zpi, Tu, Sp4);
  ew_reduce<<<dim3(4, AD, BF), 256, 0, stream>>>(SpH, cm, q, out);
}

// Round 21
// 58.582 us; speedup vs baseline: 2.6056x; 1.1814x over previous
//
#include <hip/hip_runtime.h>

namespace {
constexpr int BF = 4;        // frames
constexpr int NA = 4000;     // atoms per frame
constexpr int NPAD = 4096;   // padded K
constexpr int N8 = 512;      // NPAD/8 k-groups
constexpr int AD = 29;       // kx: 0..28
constexpr int CD = 57;       // ky/kz: -28..28
constexpr int NCH = 16;      // K-chunks (256 atoms each)
constexpr int KTC = 8;       // 32-atom k-tiles per chunk
constexpr float TWOPI_F = 6.28318530717958647692f;
constexpr float FPI = 39.47841760435743f;        // (2*pi)^2
constexpr float KSQMAX = 9.869604401089358f;     // (2*pi/2)^2
constexpr float SELF_C = 0.06349363593424097f;   // 1/(sigma*(2*pi)^1.5)
constexpr size_t YSTR = (size_t)N8 * 64 * 8;     // per-frame table elems = 262144
}

typedef short bfrag __attribute__((ext_vector_type(8)));
typedef float f32x4 __attribute__((ext_vector_type(4)));
typedef unsigned short u16x8 __attribute__((ext_vector_type(8)));
typedef unsigned u32x4 __attribute__((ext_vector_type(4)));
typedef _Float16 h2 __attribute__((ext_vector_type(2)));
typedef _Float16 h8 __attribute__((ext_vector_type(8)));

__device__ __forceinline__ unsigned short f2bf(float x) {  // RNE f32->bf16
  unsigned u = __float_as_uint(x);
  u += 0x7fffu + ((u >> 16) & 1u);
  return (unsigned short)(u >> 16);
}
__device__ __forceinline__ float2 cmul(float2 a, float2 b) {
  return make_float2(a.x * b.x - a.y * b.y, a.x * b.y + a.y * b.x);
}
__device__ __forceinline__ float2 cpow_m(float c, float s, int m) {
  float2 r = make_float2(1.f, 0.f);
  float2 x = make_float2(c, s);
  if (m & 1) r = x;
#pragma unroll
  for (int b = 1; b < 5; ++b) {
    x = cmul(x, x);
    const float2 t = cmul(r, x);
    if (m & (1 << b)) r = t;
  }
  return r;
}
__device__ __forceinline__ int swz(int byte) {   // R6-validated LDS swizzle
  return byte ^ (((byte >> 10) & 3) << 4);
}
__device__ __forceinline__ unsigned pk_h2(float a, float b) {
  union { h2 v; unsigned u; } p;
  p.v[0] = (_Float16)a; p.v[1] = (_Float16)b;
  return p.u;
}

// ---------------------------------------------------------------------------
// Fused prep (R8 bodies) + out zeroing. blockIdx.x < 128: Y/Z tables.
// blockIdx.x >= 128: T table (bf16-packed u32 [f][a][n]).
// ---------------------------------------------------------------------------
__global__ __launch_bounds__(256)
void ew_prep(const float* __restrict__ pos, const float* __restrict__ q,
             const float* __restrict__ cm,
             unsigned* __restrict__ Yp,
             unsigned short* __restrict__ Zpr, unsigned short* __restrict__ Zpi,
             unsigned* __restrict__ Tu, float* __restrict__ out)
{
  const int f = blockIdx.y;
  if (blockIdx.x == 0 && f == 0 && threadIdx.x < BF) out[threadIdx.x] = 0.f;
  if (blockIdx.x < 128) {
    const int n8 = blockIdx.x * 4 + (threadIdx.x >> 6);   // 0..511
    const int col = threadIdx.x & 63;
    const int e = col - 28;
    const int m = (e < 0) ? -e : e;
    const bool valid = col < CD;
    const float by = cm[f * 9 + 4], bz = cm[f * 9 + 8];

    unsigned yp[8];
    float zr[8], zi[8];
#pragma unroll
    for (int i = 0; i < 8; ++i) {
      const int n = n8 * 8 + i;
      const bool ok = n < NA;
      const int gn = f * NA + n;
      const float y = ok ? pos[gn * 3 + 1] : 0.f;
      const float z = ok ? pos[gn * 3 + 2] : 0.f;
      {
        float rev = y / by; rev -= floorf(rev);
        float s, c; __sincosf(TWOPI_F * rev, &s, &c);
        float2 r = cpow_m(c, s, m);
        if (e < 0) r.y = -r.y;
        const float yr = valid ? r.x : 0.f;
        const float yi = valid ? r.y : 0.f;
        yp[i] = ((unsigned)f2bf(yi) << 16) | (unsigned)f2bf(yr);
      }
      {
        float rev = z / bz; rev -= floorf(rev);
        float s, c; __sincosf(TWOPI_F * rev, &s, &c);
        float2 r = cpow_m(c, s, m);
        if (e < 0) r.y = -r.y;
        zr[i] = valid ? r.x : 0.f;
        zi[i] = valid ? r.y : 0.f;
      }
    }
    const size_t base = (size_t)f * YSTR + (size_t)n8 * 512 + (size_t)col * 8;
    *(uint4*)(Yp + base)     = make_uint4(yp[0], yp[1], yp[2], yp[3]);
    *(uint4*)(Yp + base + 4) = make_uint4(yp[4], yp[5], yp[6], yp[7]);
    u16x8 zpr, zpi;
#pragma unroll
    for (int i = 0; i < 8; ++i) { zpr[i] = f2bf(zr[i]); zpi[i] = f2bf(zi[i]); }
    *(u16x8*)(Zpr + base) = zpr;
    *(u16x8*)(Zpi + base) = zpi;
  } else {
    const int n = (blockIdx.x - 128) * 256 + threadIdx.x;   // 0..4095
    const float bx = cm[f * 9 + 0];
    const bool ok = n < NA;
    const int gn = f * NA + n;
    const float x = ok ? pos[gn * 3 + 0] : 0.f;
    const float qq = ok ? q[gn] : 0.f;
    float rev = x / bx; rev -= floorf(rev);
    float s, c; __sincosf(TWOPI_F * rev, &s, &c);
    const float2 p = make_float2(c, s);
    float2 cur = make_float2(qq, 0.f);
    unsigned* tp = Tu + (size_t)f * AD * NPAD + n;
#pragma unroll 1
    for (int a = 0; a < AD; ++a) {
      tp[(size_t)a * NPAD] = ((unsigned)f2bf(cur.y) << 16) | (unsigned)f2bf(cur.x);
      cur = cmul(cur, p);
    }
  }
}

// ---------------------------------------------------------------------------
// MFMA S-accumulation — R20 math/decode/stores, 4-buffer LDS rotation:
// 2 kt per phase, barrier per phase (4 phases, last skips) instead of 8.
// kt order preserved -> identical arithmetic to R20 (absmax 0.0625).
// ---------------------------------------------------------------------------
__global__ __launch_bounds__(256, 4)
void ew_smfma(const unsigned* __restrict__ Yp,
              const unsigned short* __restrict__ Zpr,
              const unsigned short* __restrict__ Zpi,
              const unsigned* __restrict__ Tu, u32x4* __restrict__ Sp4)
{
  // f-per-XCD-pair bijective decode (960 blocks) — R13-validated
  const int bid = blockIdx.x;
  const int xcd = bid & 7;
  const int f = xcd >> 1;                 // 2 XCDs per frame
  const int half = xcd & 1;
  const int j = bid >> 3;                 // 0..119
  const int unit = half * 120 + j;        // 0..239
  const int ch = unit / 15;               // 0..15
  const int ag = unit % 15;               // 0..14
  const int a0 = 2 * ag, a1 = a0 + 1;
  const bool has1 = a1 < AD;
  const int tid = threadIdx.x;
  const int w = tid >> 6, lane = tid & 63;
  const int g = lane >> 4, r16 = lane & 15;
  const int b0 = 16 * w;

  __shared__ unsigned short zbuf[4][2][2048];   // 32 KB, 4-deep rotation

  f32x4 S0r[4], S0i[4], S1r[4], S1i[4];
#pragma unroll
  for (int ct = 0; ct < 4; ++ct) {
    S0r[ct] = (f32x4){0.f, 0.f, 0.f, 0.f}; S0i[ct] = (f32x4){0.f, 0.f, 0.f, 0.f};
    S1r[ct] = (f32x4){0.f, 0.f, 0.f, 0.f}; S1i[ct] = (f32x4){0.f, 0.f, 0.f, 0.f};
  }

  const unsigned* ybase = Yp + (size_t)f * YSTR + (size_t)(b0 + r16) * 8
                        + (size_t)g * 512 + (size_t)ch * KTC * 2048;
  const size_t zgbase = (size_t)f * YSTR + (size_t)ch * KTC * 2048 + (size_t)tid * 8;
  const unsigned* tp0 = Tu + ((size_t)f * AD + a0) * NPAD + (size_t)ch * 256 + g * 8;
  const unsigned* tp1 = Tu + ((size_t)f * AD + (has1 ? a1 : a0)) * NPAD
                      + (size_t)ch * 256 + g * 8;

  char* const zb = (char*)&zbuf[0][0][0];
  const int wr_off = swz(tid * 16);
  const int rd_base = g * 1024 + r16 * 16;

  // ---- prologue: stage kt0 -> buf0, kt1 -> buf1 ----
  {
    const u16x8 r0 = *(const u16x8*)(Zpr + zgbase);
    const u16x8 i0 = *(const u16x8*)(Zpi + zgbase);
    const u16x8 r1 = *(const u16x8*)(Zpr + zgbase + 2048);
    const u16x8 i1 = *(const u16x8*)(Zpi + zgbase + 2048);
    *(u16x8*)(zb + wr_off) = r0;
    *(u16x8*)(zb + 4096 + wr_off) = i0;
    *(u16x8*)(zb + 8192 + wr_off) = r1;
    *(u16x8*)(zb + 12288 + wr_off) = i1;
  }
  __syncthreads();

  for (int ph = 0; ph < 4; ++ph) {
    // issue staging loads for kt+2, kt+3 (clamped; unused at ph==3)
    u16x8 zr_s0, zi_s0, zr_s1, zi_s1;
    {
      const int k2 = (2 * ph + 2 < KTC) ? (2 * ph + 2) : (KTC - 1);
      const int k3 = (2 * ph + 3 < KTC) ? (2 * ph + 3) : (KTC - 1);
      zr_s0 = *(const u16x8*)(Zpr + zgbase + (size_t)k2 * 2048);
      zi_s0 = *(const u16x8*)(Zpi + zgbase + (size_t)k2 * 2048);
      zr_s1 = *(const u16x8*)(Zpr + zgbase + (size_t)k3 * 2048);
      zi_s1 = *(const u16x8*)(Zpi + zgbase + (size_t)k3 * 2048);
    }
#pragma unroll
    for (int sub = 0; sub < 2; ++sub) {
      const int kt = 2 * ph + sub;
      const uint4 yc0 = *(const uint4*)(ybase + (size_t)kt * 2048);
      const uint4 yc1 = *(const uint4*)(ybase + (size_t)kt * 2048 + 4);
      const uint4 ta0 = *(const uint4*)(tp0 + (size_t)kt * 32);
      const uint4 ta1 = *(const uint4*)(tp0 + (size_t)kt * 32 + 4);
      const uint4 tb0 = *(const uint4*)(tp1 + (size_t)kt * 32);
      const uint4 tb1 = *(const uint4*)(tp1 + (size_t)kt * 32 + 4);

      float yr[8], yi[8];
      {
        const unsigned yu[8] = {yc0.x, yc0.y, yc0.z, yc0.w,
                                yc1.x, yc1.y, yc1.z, yc1.w};
#pragma unroll
        for (int i = 0; i < 8; ++i) {
          yr[i] = __uint_as_float(yu[i] << 16);
          yi[i] = __uint_as_float(yu[i] & 0xffff0000u);
        }
      }
      char* const cb = zb + (kt & 3) * 8192;
      const bfrag Z0r = *(const bfrag*)(cb + swz(rd_base));
      const bfrag Z1r = *(const bfrag*)(cb + swz(rd_base + 256));
      const bfrag Z2r = *(const bfrag*)(cb + swz(rd_base + 512));
      const bfrag Z3r = *(const bfrag*)(cb + swz(rd_base + 768));
      const bfrag Z0i = *(const bfrag*)(cb + 4096 + swz(rd_base));
      const bfrag Z1i = *(const bfrag*)(cb + 4096 + swz(rd_base + 256));
      const bfrag Z2i = *(const bfrag*)(cb + 4096 + swz(rd_base + 512));
      const bfrag Z3i = *(const bfrag*)(cb + 4096 + swz(rd_base + 768));

      // ---- a0 ----
      {
        const unsigned tu[8] = {ta0.x, ta0.y, ta0.z, ta0.w, ta1.x, ta1.y, ta1.z, ta1.w};
        float ur[8], ui[8];
#pragma unroll
        for (int i = 0; i < 8; ++i) {
          const float tr = __uint_as_float(tu[i] << 16);
          const float ti = __uint_as_float(tu[i] & 0xffff0000u);
          ur[i] = fmaf(tr, yr[i], -(ti * yi[i]));
          ui[i] = fmaf(tr, yi[i], ti * yr[i]);
        }
        union { unsigned u[4]; bfrag v; } UR, UI, UN;
#pragma unroll
        for (int k = 0; k < 4; ++k) {
          asm("v_cvt_pk_bf16_f32 %0, %1, %2" : "=v"(UR.u[k]) : "v"(ur[2*k]), "v"(ur[2*k+1]));
          asm("v_cvt_pk_bf16_f32 %0, %1, %2" : "=v"(UI.u[k]) : "v"(ui[2*k]), "v"(ui[2*k+1]));
        }
#pragma unroll
        for (int k = 0; k < 4; ++k) UN.u[k] = UI.u[k] ^ 0x80008000u;
        S0r[0] = __builtin_amdgcn_mfma_f32_16x16x32_bf16(UR.v, Z0r, S0r[0], 0, 0, 0);
        S0r[0] = __builtin_amdgcn_mfma_f32_16x16x32_bf16(UN.v, Z0i, S0r[0], 0, 0, 0);
        S0i[0] = __builtin_amdgcn_mfma_f32_16x16x32_bf16(UR.v, Z0i, S0i[0], 0, 0, 0);
        S0i[0] = __builtin_amdgcn_mfma_f32_16x16x32_bf16(UI.v, Z0r, S0i[0], 0, 0, 0);
        S0r[1] = __builtin_amdgcn_mfma_f32_16x16x32_bf16(UR.v, Z1r, S0r[1], 0, 0, 0);
        S0r[1] = __builtin_amdgcn_mfma_f32_16x16x32_bf16(UN.v, Z1i, S0r[1], 0, 0, 0);
        S0i[1] = __builtin_amdgcn_mfma_f32_16x16x32_bf16(UR.v, Z1i, S0i[1], 0, 0, 0);
        S0i[1] = __builtin_amdgcn_mfma_f32_16x16x32_bf16(UI.v, Z1r, S0i[1], 0, 0, 0);
        S0r[2] = __builtin_amdgcn_mfma_f32_16x16x32_bf16(UR.v, Z2r, S0r[2], 0, 0, 0);
        S0r[2] = __builtin_amdgcn_mfma_f32_16x16x32_bf16(UN.v, Z2i, S0r[2], 0, 0, 0);
        S0i[2] = __builtin_amdgcn_mfma_f32_16x16x32_bf16(UR.v, Z2i, S0i[2], 0, 0, 0);
        S0i[2] = __builtin_amdgcn_mfma_f32_16x16x32_bf16(UI.v, Z2r, S0i[2], 0, 0, 0);
        S0r[3] = __builtin_amdgcn_mfma_f32_16x16x32_bf16(UR.v, Z3r, S0r[3], 0, 0, 0);
        S0r[3] = __builtin_amdgcn_mfma_f32_16x16x32_bf16(UN.v, Z3i, S0r[3], 0, 0, 0);
        S0i[3] = __builtin_amdgcn_mfma_f32_16x16x32_bf16(UR.v, Z3i, S0i[3], 0, 0, 0);
        S0i[3] = __builtin_amdgcn_mfma_f32_16x16x32_bf16(UI.v, Z3r, S0i[3], 0, 0, 0);
      }
      // ---- a1 ----
      if (has1) {
        const unsigned tu[8] = {tb0.x, tb0.y, tb0.z, tb0.w, tb1.x, tb1.y, tb1.z, tb1.w};
        float ur[8], ui[8];
#pragma unroll
        for (int i = 0; i < 8; ++i) {
          const float tr = __uint_as_float(tu[i] << 16);
          const float ti = __uint_as_float(tu[i] & 0xffff0000u);
          ur[i] = fmaf(tr, yr[i], -(ti * yi[i]));
          ui[i] = fmaf(tr, yi[i], ti * yr[i]);
        }
        union { unsigned u[4]; bfrag v; } UR, UI, UN;
#pragma unroll
        for (int k = 0; k < 4; ++k) {
          asm("v_cvt_pk_bf16_f32 %0, %1, %2" : "=v"(UR.u[k]) : "v"(ur[2*k]), "v"(ur[2*k+1]));
          asm("v_cvt_pk_bf16_f32 %0, %1, %2" : "=v"(UI.u[k]) : "v"(ui[2*k]), "v"(ui[2*k+1]));
        }
#pragma unroll
        for (int k = 0; k < 4; ++k) UN.u[k] = UI.u[k] ^ 0x80008000u;
        S1r[0] = __builtin_amdgcn_mfma_f32_16x16x32_bf16(UR.v, Z0r, S1r[0], 0, 0, 0);
        S1r[0] = __builtin_amdgcn_mfma_f32_16x16x32_bf16(UN.v, Z0i, S1r[0], 0, 0, 0);
        S1i[0] = __builtin_amdgcn_mfma_f32_16x16x32_bf16(UR.v, Z0i, S1i[0], 0, 0, 0);
        S1i[0] = __builtin_amdgcn_mfma_f32_16x16x32_bf16(UI.v, Z0r, S1i[0], 0, 0, 0);
        S1r[1] = __builtin_amdgcn_mfma_f32_16x16x32_bf16(UR.v, Z1r, S1r[1], 0, 0, 0);
        S1r[1] = __builtin_amdgcn_mfma_f32_16x16x32_bf16(UN.v, Z1i, S1r[1], 0, 0, 0);
        S1i[1] = __builtin_amdgcn_mfma_f32_16x16x32_bf16(UR.v, Z1i, S1i[1], 0, 0, 0);
        S1i[1] = __builtin_amdgcn_mfma_f32_16x16x32_bf16(UI.v, Z1r, S1i[1], 0, 0, 0);
        S1r[2] = __builtin_amdgcn_mfma_f32_16x16x32_bf16(UR.v, Z2r, S1r[2], 0, 0, 0);
        S1r[2] = __builtin_amdgcn_mfma_f32_16x16x32_bf16(UN.v, Z2i, S1r[2], 0, 0, 0);
        S1i[2] = __builtin_amdgcn_mfma_f32_16x16x32_bf16(UR.v, Z2i, S1i[2], 0, 0, 0);
        S1i[2] = __builtin_amdgcn_mfma_f32_16x16x32_bf16(UI.v, Z2r, S1i[2], 0, 0, 0);
        S1r[3] = __builtin_amdgcn_mfma_f32_16x16x32_bf16(UR.v, Z3r, S1r[3], 0, 0, 0);
        S1r[3] = __builtin_amdgcn_mfma_f32_16x16x32_bf16(UN.v, Z3i, S1r[3], 0, 0, 0);
        S1i[3] = __builtin_amdgcn_mfma_f32_16x16x32_bf16(UR.v, Z3i, S1i[3], 0, 0, 0);
        S1i[3] = __builtin_amdgcn_mfma_f32_16x16x32_bf16(UI.v, Z3r, S1i[3], 0, 0, 0);
      }
    }
    // stage kt+2, kt+3 into the buffers just freed; barrier once per phase
    if (ph < 3) {
      char* const nb0 = zb + ((2 * ph + 2) & 3) * 8192;
      char* const nb1 = zb + ((2 * ph + 3) & 3) * 8192;
      *(u16x8*)(nb0 + wr_off) = zr_s0;
      *(u16x8*)(nb0 + 4096 + wr_off) = zi_s0;
      *(u16x8*)(nb1 + wr_off) = zr_s1;
      *(u16x8*)(nb1 + 4096 + wr_off) = zi_s1;
      __syncthreads();
    }
  }

  // ---- nontemporal 16B/lane Sp stores: e = ct*1024 + tid*4 + rg ----
  const size_t so0q = ((((size_t)ch * BF + f) * AD + a0) * 4096) >> 2;
#pragma unroll
  for (int ct = 0; ct < 4; ++ct) {
    u32x4 v;
    v[0] = pk_h2(S0r[ct][0], S0i[ct][0]);
    v[1] = pk_h2(S0r[ct][1], S0i[ct][1]);
    v[2] = pk_h2(S0r[ct][2], S0i[ct][2]);
    v[3] = pk_h2(S0r[ct][3], S0i[ct][3]);
    __builtin_nontemporal_store(v, &Sp4[so0q + ct * 256 + tid]);
  }
  if (has1) {
    const size_t so1q = ((((size_t)ch * BF + f) * AD + a1) * 4096) >> 2;
#pragma unroll
    for (int ct = 0; ct < 4; ++ct) {
      u32x4 v;
      v[0] = pk_h2(S1r[ct][0], S1i[ct][0]);
      v[1] = pk_h2(S1r[ct][1], S1i[ct][1]);
      v[2] = pk_h2(S1r[ct][2], S1i[ct][2]);
      v[3] = pk_h2(S1r[ct][3], S1i[ct][3]);
      __builtin_nontemporal_store(v, &Sp4[so1q + ct * 256 + tid]);
    }
  }
}

// ---------------------------------------------------------------------------
// Reduce — R17/R20 byte-identical (vectorized h8 loads, permuted-cell decode).
// ---------------------------------------------------------------------------
__global__ __launch_bounds__(256)
void ew_reduce(const h2* __restrict__ SpH, const float* __restrict__ cm,
               const float* __restrict__ q, float* __restrict__ out)
{
  const int a = blockIdx.y, f = blockIdx.z;
  const int t = blockIdx.x * 256 + threadIdx.x;   // 0..1023
  const int cell0 = t * 4;
  const int ct = t >> 8;
  const int tid2 = t & 255;
  const int w2 = tid2 >> 6, lane2 = tid2 & 63;
  const int c = ct * 16 + (lane2 & 15);
  const int bbase = w2 * 16 + (lane2 >> 4) * 4;   // + rg
  float Sr[4] = {0.f, 0.f, 0.f, 0.f}, Si[4] = {0.f, 0.f, 0.f, 0.f};
  const size_t base = ((size_t)f * AD + a) * 4096 + cell0;
  constexpr size_t CHSTR = (size_t)BF * AD * 4096;
#pragma unroll
  for (int ch = 0; ch < NCH; ++ch) {
    const h8 v = *(const h8*)(SpH + (size_t)ch * CHSTR + base);
#pragma unroll
    for (int k = 0; k < 4; ++k) {
      Sr[k] += (float)v[2 * k];
      Si[k] += (float)v[2 * k + 1];
    }
  }
  const float bx = cm[f * 9 + 0], by = cm[f * 9 + 4], bz = cm[f * 9 + 8];
  const float invV = 1.f / (bx * by * bz);
  const float fac = (a > 0) ? 2.f : 1.f;
  const float aterm = (float)(a * a) / (bx * bx);
  const int cv = c - 28;
  const float cterm = (float)(cv * cv) / (bz * bz);
  float val = 0.f;
#pragma unroll
  for (int k = 0; k < 4; ++k) {
    const int bv = bbase + k - 28;
    const float ksq = FPI * (aterm + (float)(bv * bv) / (by * by) + cterm);
    if (ksq > 0.f && ksq <= KSQMAX) {
      const float wgt = __expf(-0.5f * ksq) / ksq * fac * invV;
      val = fmaf(wgt, Sr[k] * Sr[k] + Si[k] * Si[k], val);
    }
  }
  for (int off = 32; off > 0; off >>= 1) val += __shfl_down(val, off);
  __shared__ float wsum[4];
  const int w = threadIdx.x >> 6;
  if ((threadIdx.x & 63) == 0) wsum[w] = val;
  __syncthreads();
  if (threadIdx.x == 0)
    atomicAdd(&out[f], wsum[0] + wsum[1] + wsum[2] + wsum[3]);

  if (a == 0 && blockIdx.x == 0) {   // fold in self-energy
    __syncthreads();
    float s = 0.f;
    for (int i = threadIdx.x; i < NA; i += 256) {
      const float qq = q[f * NA + i];
      s += qq * qq;
    }
    for (int off = 32; off > 0; off >>= 1) s += __shfl_down(s, off);
    if ((threadIdx.x & 63) == 0) wsum[w] = s;
    __syncthreads();
    if (threadIdx.x == 0)
      atomicAdd(&out[f], -(wsum[0] + wsum[1] + wsum[2] + wsum[3]) * SELF_C);
  }
}

extern "C" void kernel_launch(void* const* d_in, const int* in_sizes, int n_in,
                              void* d_out, int out_size, void* d_ws, size_t ws_size,
                              hipStream_t stream) {
  const float* pos = (const float*)d_in[0];   // (B*N, 3)
  const float* q   = (const float*)d_in[1];   // (B*N, 1)
  const float* cm  = (const float*)d_in[2];   // (B, 3, 3)
  float* out = (float*)d_out;                 // (B,)

  char* ws = (char*)d_ws;
  const size_t MB = 1024 * 1024;
  unsigned* Yp = (unsigned*)(ws);                         // 4 MB
  unsigned short* Zpr = (unsigned short*)(ws + 4 * MB);   // 2 MB
  unsigned short* Zpi = (unsigned short*)(ws + 6 * MB);   // 2 MB
  unsigned* Tu = (unsigned*)(ws + 8 * MB);                // 1.9 MB
  h2* SpH = (h2*)(ws + 10 * MB);                          // 30.4 MB
  u32x4* Sp4 = (u32x4*)SpH;

  ew_prep<<<dim3(144, BF), 256, 0, stream>>>(pos, q, cm, Yp, Zpr, Zpi, Tu, out);
  ew_smfma<<<dim3(960), 256, 0, stream>>>(Yp, Zpr, Zpi, Tu, Sp4);
  ew_reduce<<<dim3(4, AD, BF), 256, 0, stream>>>(SpH, cm, q, out);
}

// Round 22
// 52.644 us; speedup vs baseline: 2.8995x; 1.1128x over previous
//
#include <hip/hip_runtime.h>

namespace {
constexpr int BF = 4;        // frames
constexpr int NA = 4000;     // atoms per frame
constexpr int NPAD = 4096;   // padded K
constexpr int N8 = 512;      // NPAD/8 k-groups
constexpr int AD = 29;       // kx: 0..28
constexpr int CD = 57;       // ky/kz: -28..28
constexpr int NCH = 16;      // K-chunks (256 atoms each)
constexpr int KTC = 8;       // 32-atom k-tiles per chunk
constexpr float TWOPI_F = 6.28318530717958647692f;
constexpr float FPI = 39.47841760435743f;        // (2*pi)^2
constexpr float KSQMAX = 9.869604401089358f;     // (2*pi/2)^2
constexpr float SELF_C = 0.06349363593424097f;   // 1/(sigma*(2*pi)^1.5)
constexpr size_t YSTR = (size_t)N8 * 64 * 8;     // per-frame table elems = 262144
}

typedef short bfrag __attribute__((ext_vector_type(8)));
typedef float f32x4 __attribute__((ext_vector_type(4)));
typedef unsigned short u16x8 __attribute__((ext_vector_type(8)));
typedef unsigned u32x4 __attribute__((ext_vector_type(4)));
typedef _Float16 h2 __attribute__((ext_vector_type(2)));
typedef _Float16 h8 __attribute__((ext_vector_type(8)));

__device__ __forceinline__ unsigned short f2bf(float x) {  // RNE f32->bf16
  unsigned u = __float_as_uint(x);
  u += 0x7fffu + ((u >> 16) & 1u);
  return (unsigned short)(u >> 16);
}
__device__ __forceinline__ float2 cmul(float2 a, float2 b) {
  return make_float2(a.x * b.x - a.y * b.y, a.x * b.y + a.y * b.x);
}
__device__ __forceinline__ float2 cpow_m(float c, float s, int m) {
  float2 r = make_float2(1.f, 0.f);
  float2 x = make_float2(c, s);
  if (m & 1) r = x;
#pragma unroll
  for (int b = 1; b < 5; ++b) {
    x = cmul(x, x);
    const float2 t = cmul(r, x);
    if (m & (1 << b)) r = t;
  }
  return r;
}
__device__ __forceinline__ int swz(int byte) {   // R6-validated LDS swizzle
  return byte ^ (((byte >> 10) & 3) << 4);
}
__device__ __forceinline__ unsigned pk_h2(float a, float b) {
  union { h2 v; unsigned u; } p;
  p.v[0] = (_Float16)a; p.v[1] = (_Float16)b;
  return p.u;
}

// ---------------------------------------------------------------------------
// Fused prep (R8 bodies) + out zeroing. blockIdx.x < 128: Y/Z tables.
// blockIdx.x >= 128: T table (bf16-packed u32 [f][a][n]).
// ---------------------------------------------------------------------------
__global__ __launch_bounds__(256)
void ew_prep(const float* __restrict__ pos, const float* __restrict__ q,
             const float* __restrict__ cm,
             unsigned* __restrict__ Yp,
             unsigned short* __restrict__ Zpr, unsigned short* __restrict__ Zpi,
             unsigned* __restrict__ Tu, float* __restrict__ out)
{
  const int f = blockIdx.y;
  if (blockIdx.x == 0 && f == 0 && threadIdx.x < BF) out[threadIdx.x] = 0.f;
  if (blockIdx.x < 128) {
    const int n8 = blockIdx.x * 4 + (threadIdx.x >> 6);   // 0..511
    const int col = threadIdx.x & 63;
    const int e = col - 28;
    const int m = (e < 0) ? -e : e;
    const bool valid = col < CD;
    const float by = cm[f * 9 + 4], bz = cm[f * 9 + 8];

    unsigned yp[8];
    float zr[8], zi[8];
#pragma unroll
    for (int i = 0; i < 8; ++i) {
      const int n = n8 * 8 + i;
      const bool ok = n < NA;
      const int gn = f * NA + n;
      const float y = ok ? pos[gn * 3 + 1] : 0.f;
      const float z = ok ? pos[gn * 3 + 2] : 0.f;
      {
        float rev = y / by; rev -= floorf(rev);
        float s, c; __sincosf(TWOPI_F * rev, &s, &c);
        float2 r = cpow_m(c, s, m);
        if (e < 0) r.y = -r.y;
        const float yr = valid ? r.x : 0.f;
        const float yi = valid ? r.y : 0.f;
        yp[i] = ((unsigned)f2bf(yi) << 16) | (unsigned)f2bf(yr);
      }
      {
        float rev = z / bz; rev -= floorf(rev);
        float s, c; __sincosf(TWOPI_F * rev, &s, &c);
        float2 r = cpow_m(c, s, m);
        if (e < 0) r.y = -r.y;
        zr[i] = valid ? r.x : 0.f;
        zi[i] = valid ? r.y : 0.f;
      }
    }
    const size_t base = (size_t)f * YSTR + (size_t)n8 * 512 + (size_t)col * 8;
    *(uint4*)(Yp + base)     = make_uint4(yp[0], yp[1], yp[2], yp[3]);
    *(uint4*)(Yp + base + 4) = make_uint4(yp[4], yp[5], yp[6], yp[7]);
    u16x8 zpr, zpi;
#pragma unroll
    for (int i = 0; i < 8; ++i) { zpr[i] = f2bf(zr[i]); zpi[i] = f2bf(zi[i]); }
    *(u16x8*)(Zpr + base) = zpr;
    *(u16x8*)(Zpi + base) = zpi;
  } else {
    const int n = (blockIdx.x - 128) * 256 + threadIdx.x;   // 0..4095
    const float bx = cm[f * 9 + 0];
    const bool ok = n < NA;
    const int gn = f * NA + n;
    const float x = ok ? pos[gn * 3 + 0] : 0.f;
    const float qq = ok ? q[gn] : 0.f;
    float rev = x / bx; rev -= floorf(rev);
    float s, c; __sincosf(TWOPI_F * rev, &s, &c);
    const float2 p = make_float2(c, s);
    float2 cur = make_float2(qq, 0.f);
    unsigned* tp = Tu + (size_t)f * AD * NPAD + n;
#pragma unroll 1
    for (int a = 0; a < AD; ++a) {
      tp[(size_t)a * NPAD] = ((unsigned)f2bf(cur.y) << 16) | (unsigned)f2bf(cur.x);
      cur = cmul(cur, p);
    }
  }
}

// ---------------------------------------------------------------------------
// MFMA S-accumulation — R21 math/decode/stores, full-chunk LDS staging:
// all 8 kt staged in the prologue (64 KB), ONE barrier, then a barrier-free
// compute loop. kt order preserved -> identical arithmetic (absmax 0.0625).
// ---------------------------------------------------------------------------
__global__ __launch_bounds__(256, 2)
void ew_smfma(const unsigned* __restrict__ Yp,
              const unsigned short* __restrict__ Zpr,
              const unsigned short* __restrict__ Zpi,
              const unsigned* __restrict__ Tu, u32x4* __restrict__ Sp4)
{
  // f-per-XCD-pair bijective decode (960 blocks) — R13-validated
  const int bid = blockIdx.x;
  const int xcd = bid & 7;
  const int f = xcd >> 1;                 // 2 XCDs per frame
  const int half = xcd & 1;
  const int j = bid >> 3;                 // 0..119
  const int unit = half * 120 + j;        // 0..239
  const int ch = unit / 15;               // 0..15
  const int ag = unit % 15;               // 0..14
  const int a0 = 2 * ag, a1 = a0 + 1;
  const bool has1 = a1 < AD;
  const int tid = threadIdx.x;
  const int w = tid >> 6, lane = tid & 63;
  const int g = lane >> 4, r16 = lane & 15;
  const int b0 = 16 * w;

  __shared__ unsigned short zbuf[8][2][2048];   // 64 KB, full chunk

  f32x4 S0r[4], S0i[4], S1r[4], S1i[4];
#pragma unroll
  for (int ct = 0; ct < 4; ++ct) {
    S0r[ct] = (f32x4){0.f, 0.f, 0.f, 0.f}; S0i[ct] = (f32x4){0.f, 0.f, 0.f, 0.f};
    S1r[ct] = (f32x4){0.f, 0.f, 0.f, 0.f}; S1i[ct] = (f32x4){0.f, 0.f, 0.f, 0.f};
  }

  const unsigned* ybase = Yp + (size_t)f * YSTR + (size_t)(b0 + r16) * 8
                        + (size_t)g * 512 + (size_t)ch * KTC * 2048;
  const size_t zgbase = (size_t)f * YSTR + (size_t)ch * KTC * 2048 + (size_t)tid * 8;
  const unsigned* tp0 = Tu + ((size_t)f * AD + a0) * NPAD + (size_t)ch * 256 + g * 8;
  const unsigned* tp1 = Tu + ((size_t)f * AD + (has1 ? a1 : a0)) * NPAD
                      + (size_t)ch * 256 + g * 8;

  char* const zb = (char*)&zbuf[0][0][0];
  const int wr_off = swz(tid * 16);
  const int rd_base = g * 1024 + r16 * 16;

  // ---- prologue: stage the whole chunk (16 loads in flight), one barrier ----
#pragma unroll
  for (int kt = 0; kt < KTC; ++kt) {
    const u16x8 r = *(const u16x8*)(Zpr + zgbase + (size_t)kt * 2048);
    const u16x8 i = *(const u16x8*)(Zpi + zgbase + (size_t)kt * 2048);
    char* const nb = zb + kt * 8192;
    *(u16x8*)(nb + wr_off) = r;
    *(u16x8*)(nb + 4096 + wr_off) = i;
  }
  __syncthreads();

  // ---- barrier-free compute loop ----
#pragma unroll 2
  for (int kt = 0; kt < KTC; ++kt) {
    const uint4 yc0 = *(const uint4*)(ybase + (size_t)kt * 2048);
    const uint4 yc1 = *(const uint4*)(ybase + (size_t)kt * 2048 + 4);
    const uint4 ta0 = *(const uint4*)(tp0 + (size_t)kt * 32);
    const uint4 ta1 = *(const uint4*)(tp0 + (size_t)kt * 32 + 4);
    const uint4 tb0 = *(const uint4*)(tp1 + (size_t)kt * 32);
    const uint4 tb1 = *(const uint4*)(tp1 + (size_t)kt * 32 + 4);

    float yr[8], yi[8];
    {
      const unsigned yu[8] = {yc0.x, yc0.y, yc0.z, yc0.w,
                              yc1.x, yc1.y, yc1.z, yc1.w};
#pragma unroll
      for (int i = 0; i < 8; ++i) {
        yr[i] = __uint_as_float(yu[i] << 16);
        yi[i] = __uint_as_float(yu[i] & 0xffff0000u);
      }
    }
    char* const cb = zb + kt * 8192;
    const bfrag Z0r = *(const bfrag*)(cb + swz(rd_base));
    const bfrag Z1r = *(const bfrag*)(cb + swz(rd_base + 256));
    const bfrag Z2r = *(const bfrag*)(cb + swz(rd_base + 512));
    const bfrag Z3r = *(const bfrag*)(cb + swz(rd_base + 768));
    const bfrag Z0i = *(const bfrag*)(cb + 4096 + swz(rd_base));
    const bfrag Z1i = *(const bfrag*)(cb + 4096 + swz(rd_base + 256));
    const bfrag Z2i = *(const bfrag*)(cb + 4096 + swz(rd_base + 512));
    const bfrag Z3i = *(const bfrag*)(cb + 4096 + swz(rd_base + 768));

    // ---- a0 ----
    {
      const unsigned tu[8] = {ta0.x, ta0.y, ta0.z, ta0.w, ta1.x, ta1.y, ta1.z, ta1.w};
      float ur[8], ui[8];
#pragma unroll
      for (int i = 0; i < 8; ++i) {
        const float tr = __uint_as_float(tu[i] << 16);
        const float ti = __uint_as_float(tu[i] & 0xffff0000u);
        ur[i] = fmaf(tr, yr[i], -(ti * yi[i]));
        ui[i] = fmaf(tr, yi[i], ti * yr[i]);
      }
      union { unsigned u[4]; bfrag v; } UR, UI, UN;
#pragma unroll
      for (int k = 0; k < 4; ++k) {
        asm("v_cvt_pk_bf16_f32 %0, %1, %2" : "=v"(UR.u[k]) : "v"(ur[2*k]), "v"(ur[2*k+1]));
        asm("v_cvt_pk_bf16_f32 %0, %1, %2" : "=v"(UI.u[k]) : "v"(ui[2*k]), "v"(ui[2*k+1]));
      }
#pragma unroll
      for (int k = 0; k < 4; ++k) UN.u[k] = UI.u[k] ^ 0x80008000u;
      S0r[0] = __builtin_amdgcn_mfma_f32_16x16x32_bf16(UR.v, Z0r, S0r[0], 0, 0, 0);
      S0r[0] = __builtin_amdgcn_mfma_f32_16x16x32_bf16(UN.v, Z0i, S0r[0], 0, 0, 0);
      S0i[0] = __builtin_amdgcn_mfma_f32_16x16x32_bf16(UR.v, Z0i, S0i[0], 0, 0, 0);
      S0i[0] = __builtin_amdgcn_mfma_f32_16x16x32_bf16(UI.v, Z0r, S0i[0], 0, 0, 0);
      S0r[1] = __builtin_amdgcn_mfma_f32_16x16x32_bf16(UR.v, Z1r, S0r[1], 0, 0, 0);
      S0r[1] = __builtin_amdgcn_mfma_f32_16x16x32_bf16(UN.v, Z1i, S0r[1], 0, 0, 0);
      S0i[1] = __builtin_amdgcn_mfma_f32_16x16x32_bf16(UR.v, Z1i, S0i[1], 0, 0, 0);
      S0i[1] = __builtin_amdgcn_mfma_f32_16x16x32_bf16(UI.v, Z1r, S0i[1], 0, 0, 0);
      S0r[2] = __builtin_amdgcn_mfma_f32_16x16x32_bf16(UR.v, Z2r, S0r[2], 0, 0, 0);
      S0r[2] = __builtin_amdgcn_mfma_f32_16x16x32_bf16(UN.v, Z2i, S0r[2], 0, 0, 0);
      S0i[2] = __builtin_amdgcn_mfma_f32_16x16x32_bf16(UR.v, Z2i, S0i[2], 0, 0, 0);
      S0i[2] = __builtin_amdgcn_mfma_f32_16x16x32_bf16(UI.v, Z2r, S0i[2], 0, 0, 0);
      S0r[3] = __builtin_amdgcn_mfma_f32_16x16x32_bf16(UR.v, Z3r, S0r[3], 0, 0, 0);
      S0r[3] = __builtin_amdgcn_mfma_f32_16x16x32_bf16(UN.v, Z3i, S0r[3], 0, 0, 0);
      S0i[3] = __builtin_amdgcn_mfma_f32_16x16x32_bf16(UR.v, Z3i, S0i[3], 0, 0, 0);
      S0i[3] = __builtin_amdgcn_mfma_f32_16x16x32_bf16(UI.v, Z3r, S0i[3], 0, 0, 0);
    }
    // ---- a1 ----
    if (has1) {
      const unsigned tu[8] = {tb0.x, tb0.y, tb0.z, tb0.w, tb1.x, tb1.y, tb1.z, tb1.w};
      float ur[8], ui[8];
#pragma unroll
      for (int i = 0; i < 8; ++i) {
        const float tr = __uint_as_float(tu[i] << 16);
        const float ti = __uint_as_float(tu[i] & 0xffff0000u);
        ur[i] = fmaf(tr, yr[i], -(ti * yi[i]));
        ui[i] = fmaf(tr, yi[i], ti * yr[i]);
      }
      union { unsigned u[4]; bfrag v; } UR, UI, UN;
#pragma unroll
      for (int k = 0; k < 4; ++k) {
        asm("v_cvt_pk_bf16_f32 %0, %1, %2" : "=v"(UR.u[k]) : "v"(ur[2*k]), "v"(ur[2*k+1]));
        asm("v_cvt_pk_bf16_f32 %0, %1, %2" : "=v"(UI.u[k]) : "v"(ui[2*k]), "v"(ui[2*k+1]));
      }
#pragma unroll
      for (int k = 0; k < 4; ++k) UN.u[k] = UI.u[k] ^ 0x80008000u;
      S1r[0] = __builtin_amdgcn_mfma_f32_16x16x32_bf16(UR.v, Z0r, S1r[0], 0, 0, 0);
      S1r[0] = __builtin_amdgcn_mfma_f32_16x16x32_bf16(UN.v, Z0i, S1r[0], 0, 0, 0);
      S1i[0] = __builtin_amdgcn_mfma_f32_16x16x32_bf16(UR.v, Z0i, S1i[0], 0, 0, 0);
      S1i[0] = __builtin_amdgcn_mfma_f32_16x16x32_bf16(UI.v, Z0r, S1i[0], 0, 0, 0);
      S1r[1] = __builtin_amdgcn_mfma_f32_16x16x32_bf16(UR.v, Z1r, S1r[1], 0, 0, 0);
      S1r[1] = __builtin_amdgcn_mfma_f32_16x16x32_bf16(UN.v, Z1i, S1r[1], 0, 0, 0);
      S1i[1] = __builtin_amdgcn_mfma_f32_16x16x32_bf16(UR.v, Z1i, S1i[1], 0, 0, 0);
      S1i[1] = __builtin_amdgcn_mfma_f32_16x16x32_bf16(UI.v, Z1r, S1i[1], 0, 0, 0);
      S1r[2] = __builtin_amdgcn_mfma_f32_16x16x32_bf16(UR.v, Z2r, S1r[2], 0, 0, 0);
      S1r[2] = __builtin_amdgcn_mfma_f32_16x16x32_bf16(UN.v, Z2i, S1r[2], 0, 0, 0);
      S1i[2] = __builtin_amdgcn_mfma_f32_16x16x32_bf16(UR.v, Z2i, S1i[2], 0, 0, 0);
      S1i[2] = __builtin_amdgcn_mfma_f32_16x16x32_bf16(UI.v, Z2r, S1i[2], 0, 0, 0);
      S1r[3] = __builtin_amdgcn_mfma_f32_16x16x32_bf16(UR.v, Z3r, S1r[3], 0, 0, 0);
      S1r[3] = __builtin_amdgcn_mfma_f32_16x16x32_bf16(UN.v, Z3i, S1r[3], 0, 0, 0);
      S1i[3] = __builtin_amdgcn_mfma_f32_16x16x32_bf16(UR.v, Z3i, S1i[3], 0, 0, 0);
      S1i[3] = __builtin_amdgcn_mfma_f32_16x16x32_bf16(UI.v, Z3r, S1i[3], 0, 0, 0);
    }
  }

  // ---- nontemporal 16B/lane Sp stores: e = ct*1024 + tid*4 + rg ----
  const size_t so0q = ((((size_t)ch * BF + f) * AD + a0) * 4096) >> 2;
#pragma unroll
  for (int ct = 0; ct < 4; ++ct) {
    u32x4 v;
    v[0] = pk_h2(S0r[ct][0], S0i[ct][0]);
    v[1] = pk_h2(S0r[ct][1], S0i[ct][1]);
    v[2] = pk_h2(S0r[ct][2], S0i[ct][2]);
    v[3] = pk_h2(S0r[ct][3], S0i[ct][3]);
    __builtin_nontemporal_store(v, &Sp4[so0q + ct * 256 + tid]);
  }
  if (has1) {
    const size_t so1q = ((((size_t)ch * BF + f) * AD + a1) * 4096) >> 2;
#pragma unroll
    for (int ct = 0; ct < 4; ++ct) {
      u32x4 v;
      v[0] = pk_h2(S1r[ct][0], S1i[ct][0]);
      v[1] = pk_h2(S1r[ct][1], S1i[ct][1]);
      v[2] = pk_h2(S1r[ct][2], S1i[ct][2]);
      v[3] = pk_h2(S1r[ct][3], S1i[ct][3]);
      __builtin_nontemporal_store(v, &Sp4[so1q + ct * 256 + tid]);
    }
  }
}

// ---------------------------------------------------------------------------
// Reduce — R17/R20 byte-identical (vectorized h8 loads, permuted-cell decode).
// ---------------------------------------------------------------------------
__global__ __launch_bounds__(256)
void ew_reduce(const h2* __restrict__ SpH, const float* __restrict__ cm,
               const float* __restrict__ q, float* __restrict__ out)
{
  const int a = blockIdx.y, f = blockIdx.z;
  const int t = blockIdx.x * 256 + threadIdx.x;   // 0..1023
  const int cell0 = t * 4;
  const int ct = t >> 8;
  const int tid2 = t & 255;
  const int w2 = tid2 >> 6, lane2 = tid2 & 63;
  const int c = ct * 16 + (lane2 & 15);
  const int bbase = w2 * 16 + (lane2 >> 4) * 4;   // + rg
  float Sr[4] = {0.f, 0.f, 0.f, 0.f}, Si[4] = {0.f, 0.f, 0.f, 0.f};
  const size_t base = ((size_t)f * AD + a) * 4096 + cell0;
  constexpr size_t CHSTR = (size_t)BF * AD * 4096;
#pragma unroll
  for (int ch = 0; ch < NCH; ++ch) {
    const h8 v = *(const h8*)(SpH + (size_t)ch * CHSTR + base);
#pragma unroll
    for (int k = 0; k < 4; ++k) {
      Sr[k] += (float)v[2 * k];
      Si[k] += (float)v[2 * k + 1];
    }
  }
  const float bx = cm[f * 9 + 0], by = cm[f * 9 + 4], bz = cm[f * 9 + 8];
  const float invV = 1.f / (bx * by * bz);
  const float fac = (a > 0) ? 2.f : 1.f;
  const float aterm = (float)(a * a) / (bx * bx);
  const int cv = c - 28;
  const float cterm = (float)(cv * cv) / (bz * bz);
  float val = 0.f;
#pragma unroll
  for (int k = 0; k < 4; ++k) {
    const int bv = bbase + k - 28;
    const float ksq = FPI * (aterm + (float)(bv * bv) / (by * by) + cterm);
    if (ksq > 0.f && ksq <= KSQMAX) {
      const float wgt = __expf(-0.5f * ksq) / ksq * fac * invV;
      val = fmaf(wgt, Sr[k] * Sr[k] + Si[k] * Si[k], val);
    }
  }
  for (int off = 32; off > 0; off >>= 1) val += __shfl_down(val, off);
  __shared__ float wsum[4];
  const int w = threadIdx.x >> 6;
  if ((threadIdx.x & 63) == 0) wsum[w] = val;
  __syncthreads();
  if (threadIdx.x == 0)
    atomicAdd(&out[f], wsum[0] + wsum[1] + wsum[2] + wsum[3]);

  if (a == 0 && blockIdx.x == 0) {   // fold in self-energy
    __syncthreads();
    float s = 0.f;
    for (int i = threadIdx.x; i < NA; i += 256) {
      const float qq = q[f * NA + i];
      s += qq * qq;
    }
    for (int off = 32; off > 0; off >>= 1) s += __shfl_down(s, off);
    if ((threadIdx.x & 63) == 0) wsum[w] = s;
    __syncthreads();
    if (threadIdx.x == 0)
      atomicAdd(&out[f], -(wsum[0] + wsum[1] + wsum[2] + wsum[3]) * SELF_C);
  }
}

extern "C" void kernel_launch(void* const* d_in, const int* in_sizes, int n_in,
                              void* d_out, int out_size, void* d_ws, size_t ws_size,
                              hipStream_t stream) {
  const float* pos = (const float*)d_in[0];   // (B*N, 3)
  const float* q   = (const float*)d_in[1];   // (B*N, 1)
  const float* cm  = (const float*)d_in[2];   // (B, 3, 3)
  float* out = (float*)d_out;                 // (B,)

  char* ws = (char*)d_ws;
  const size_t MB = 1024 * 1024;
  unsigned* Yp = (unsigned*)(ws);                         // 4 MB
  unsigned short* Zpr = (unsigned short*)(ws + 4 * MB);   // 2 MB
  unsigned short* Zpi = (unsigned short*)(ws + 6 * MB);   // 2 MB
  unsigned* Tu = (unsigned*)(ws + 8 * MB);                // 1.9 MB
  h2* SpH = (h2*)(ws + 10 * MB);                          // 30.4 MB
  u32x4* Sp4 = (u32x4*)SpH;

  ew_prep<<<dim3(144, BF), 256, 0, stream>>>(pos, q, cm, Yp, Zpr, Zpi, Tu, out);
  ew_smfma<<<dim3(960), 256, 0, stream>>>(Yp, Zpr, Zpi, Tu, Sp4);
  ew_reduce<<<dim3(4, AD, BF), 256, 0, stream>>>(SpH, cm, q, out);
}